// Round 19
// baseline (235.441 us; speedup 1.0000x reference)
//
#include <hip/hip_runtime.h>
#include <math.h>

typedef _Float16 f16;
typedef f16 f16x8 __attribute__((ext_vector_type(8)));
typedef float f32x4 __attribute__((ext_vector_type(4)));

namespace {
constexpr int B_ = 2, C_ = 48, H_ = 64, W_ = 64;
constexpr int N_ = H_ * W_;    // 4096
constexpr int NP_ = 1024;      // 32*32
constexpr int C4_ = 4 * C_;    // 192
constexpr float EPS_ = 1e-5f;
constexpr float L2E_ = 1.44269504f;
constexpr float REFL2_ = -25.0f * 1.44269504f;  // REF * log2(e), REF = -25
}

#define MFMA32(a, b, c) __builtin_amdgcn_mfma_f32_16x16x32_f16((a), (b), (c), 0, 0, 0)

__device__ inline float fast_exp2(float x) {
#if __has_builtin(__builtin_amdgcn_exp2f)
  return __builtin_amdgcn_exp2f(x);
#else
  float r;
  asm("v_exp_f32 %0, %1" : "=v"(r) : "v"(x));
  return r;
#endif
}

// ---------------- projection body (shared by global/patch)
__device__ __attribute__((always_inline)) void proj_body(
    const float* __restrict__ xb, const float* __restrict__ Ws,
    f16* __restrict__ pnb, size_t pn_stride, f16* __restrict__ ptb) {
  float acc[48];
#pragma unroll
  for (int d = 0; d < 48; ++d) acc[d] = 0.f;
  for (int c0 = 0; c0 < 48; c0 += 4) {
    float xv0 = xb[(size_t)(c0 + 0) * 4096];
    float xv1 = xb[(size_t)(c0 + 1) * 4096];
    float xv2 = xb[(size_t)(c0 + 2) * 4096];
    float xv3 = xb[(size_t)(c0 + 3) * 4096];
#pragma unroll
    for (int d = 0; d < 48; ++d) {
      const float4 wv = *(const float4*)&Ws[d * 48 + c0];
      acc[d] = fmaf(wv.x, xv0, fmaf(wv.y, xv1, fmaf(wv.z, xv2, fmaf(wv.w, xv3, acc[d]))));
    }
  }
#pragma unroll
  for (int d = 0; d < 48; ++d) pnb[(size_t)d * pn_stride] = (f16)acc[d];
#pragma unroll
  for (int s = 0; s < 6; ++s) {
    f16x8 v;
#pragma unroll
    for (int j = 0; j < 8; ++j) v[j] = (f16)acc[s * 8 + j];
    *(f16x8*)(ptb + s * 8) = v;
  }
  f16x8 zv = {0, 0, 0, 0, 0, 0, 0, 0};
  *(f16x8*)(ptb + 48) = zv;
  *(f16x8*)(ptb + 56) = zv;
}

// ---------------- merged projections: blocks [0,128) global, [128,416) patch
__global__ __launch_bounds__(256) void k_proj_all(
    const float* __restrict__ x0, const float* __restrict__ x1,
    const float* __restrict__ x2, const float* __restrict__ x3,
    const float* __restrict__ w0, const float* __restrict__ w1,
    const float* __restrict__ w2, const float* __restrict__ w3,
    const float* __restrict__ wp0, const float* __restrict__ wp1,
    const float* __restrict__ wp2, const float* __restrict__ wp3,
    f16* __restrict__ pgn, f16* __restrict__ pgt,
    f16* __restrict__ ppn, f16* __restrict__ ppt) {
  __shared__ float Ws[48 * 48];
  int tid = threadIdx.x;
  int bid = blockIdx.x;
  if (bid < 128) {
    int bx = bid & 15, b = (bid >> 4) & 1, X = bid >> 5;
    const float* xp = X == 0 ? x0 : X == 1 ? x1 : X == 2 ? x2 : x3;
    const float* wp = X == 0 ? w0 : X == 1 ? w1 : X == 2 ? w2 : w3;
    for (int i = tid; i < 2304; i += 256) Ws[i] = wp[i];
    __syncthreads();
    int n = bx * 256 + tid;
    int z2 = X * 2 + b;
    proj_body(xp + (size_t)b * 48 * 4096 + n, Ws,
              pgn + ((size_t)z2 * 48) * 4096 + n, 4096,
              pgt + ((size_t)z2 * 4096 + n) * 64);
  } else {
    int pid = bid - 128;
    int bx = pid & 3;
    int rest = pid >> 2;
    int p = rest % 9;
    int zb = rest / 9;
    int X = zb >> 1, b = zb & 1;
    const float* xp = X == 0 ? x0 : X == 1 ? x1 : X == 2 ? x2 : x3;
    const float* wp = (X == 0 ? wp0 : X == 1 ? wp1 : X == 2 ? wp2 : wp3) + (size_t)p * 2304;
    for (int i = tid; i < 2304; i += 256) Ws[i] = wp[i];
    __syncthreads();
    int t = bx * 256 + tid;
    int r0 = (p / 3) * 16, c0w = (p % 3) * 16;
    int rr = r0 + (t >> 5), cc = c0w + (t & 31);
    int z9 = (X * 2 + b) * 9 + p;
    proj_body(xp + (size_t)b * 48 * 4096 + rr * 64 + cc, Ws,
              ppn + ((size_t)z9 * 48) * 1024 + t, 1024,
              ppt + ((size_t)z9 * 1024 + t) * 64);
  }
}

// ---------------- stats body: partial Z[n] = sum_{m in chunk} exp(REF - e[n,m])
template <int NT, int NSPLIT, bool PATCH>
__device__ __attribute__((always_inline)) void stats_body(
    const f16* __restrict__ qT_all, const f16* __restrict__ kT_all,
    float* __restrict__ stp, int bx, int by, uint4* Ks) {
  constexpr int MTI = (NT / NSPLIT) / 64;
  int tid = threadIdx.x, wave = tid >> 6, lane = tid & 63, g = lane >> 4, lm = lane & 15;
  int ms = by % NSPLIT, z = by / NSPLIT;
  const f16* qT;
  if (PATCH) {
    int b = (z / 9) % 2, p = z % 9;
    qT = qT_all + ((size_t)(b * 9 + p)) * NT * 64;
  } else {
    int b = z & 1;
    qT = qT_all + (size_t)b * NT * 64;
  }
  const f16* kT = kT_all + (size_t)z * NT * 64;
  int n0 = bx * 128 + wave * 16;  // tile a; tile b = n0 + 64
  f16x8 aq0a = *(const f16x8*)(qT + (size_t)(n0 + lm) * 64 + g * 8);
  f16x8 aq1a = *(const f16x8*)(qT + (size_t)(n0 + lm) * 64 + 32 + g * 8);
  f16x8 aq0b = *(const f16x8*)(qT + (size_t)(n0 + 64 + lm) * 64 + g * 8);
  f16x8 aq1b = *(const f16x8*)(qT + (size_t)(n0 + 64 + lm) * 64 + 32 + g * 8);
  const int s0r = tid >> 3, s0c = (tid & 7) * 8;
  const int sw0 = tid ^ ((tid >> 3) & 7);
  const int sw1 = (tid + 256) ^ (((tid + 256) >> 3) & 7);
  const int swl = lm & 7;
  const int c0i = g ^ swl, c1i = (4 + g) ^ swl;
  int t_beg = ms * MTI;
  {
    const f16* src = kT + (size_t)t_beg * 64 * 64;
    Ks[sw0] = *(const uint4*)(src + (size_t)s0r * 64 + s0c);
    Ks[sw1] = *(const uint4*)(src + (size_t)(s0r + 32) * 64 + s0c);
  }
  __syncthreads();
  float zsa[4] = {0.f, 0.f, 0.f, 0.f};
  float zsb[4] = {0.f, 0.f, 0.f, 0.f};
  for (int mt = 0; mt < MTI; ++mt) {
    int cur = mt & 1;
    bool pf = (mt + 1 < MTI);
    uint4 k0v, k1v;
    if (pf) {
      const f16* src = kT + (size_t)(t_beg + mt + 1) * 64 * 64;
      k0v = *(const uint4*)(src + (size_t)s0r * 64 + s0c);
      k1v = *(const uint4*)(src + (size_t)(s0r + 32) * 64 + s0c);
    }
    uint4* kb = Ks + cur * 512;
    __builtin_amdgcn_s_setprio(1);
#pragma unroll
    for (int mf = 0; mf < 4; ++mf) {
      f16x8 b0 = __builtin_bit_cast(f16x8, kb[(16 * mf + lm) * 8 + c0i]);
      f16x8 b1 = __builtin_bit_cast(f16x8, kb[(16 * mf + lm) * 8 + c1i]);
      f32x4 ea = {0.f, 0.f, 0.f, 0.f};
      ea = MFMA32(aq0a, b0, ea);
      ea = MFMA32(aq1a, b1, ea);
      f32x4 eb = {0.f, 0.f, 0.f, 0.f};
      eb = MFMA32(aq0b, b0, eb);
      eb = MFMA32(aq1b, b1, eb);
#pragma unroll
      for (int r = 0; r < 4; ++r) {
        zsa[r] += fast_exp2(fmaf(ea[r], -L2E_, REFL2_));
        zsb[r] += fast_exp2(fmaf(eb[r], -L2E_, REFL2_));
      }
    }
    __builtin_amdgcn_s_setprio(0);
    if (pf) {
      uint4* kn = Ks + (cur ^ 1) * 512;
      kn[sw0] = k0v;
      kn[sw1] = k1v;
    }
    __syncthreads();
  }
#pragma unroll
  for (int mask = 1; mask < 16; mask <<= 1) {
#pragma unroll
    for (int r = 0; r < 4; ++r) {
      zsa[r] += __shfl_xor(zsa[r], mask, 64);
      zsb[r] += __shfl_xor(zsb[r], mask, 64);
    }
  }
  if (lm == 0) {
#pragma unroll
    for (int r = 0; r < 4; ++r) {
      stp[((size_t)z * NT + n0 + 4 * g + r) * NSPLIT + ms] = zsa[r];
      stp[((size_t)z * NT + n0 + 64 + 4 * g + r) * NSPLIT + ms] = zsb[r];
    }
  }
}

// ---------------- merged stats: blocks [0,1024) global, [1024,1600) patch
__global__ __launch_bounds__(256, 6) void k_stats_all(
    const f16* __restrict__ pg_t, float* __restrict__ stpg,
    const f16* __restrict__ pp_t, float* __restrict__ stpp) {
  __shared__ uint4 Ks[2 * 512];
  int bid = blockIdx.x;
  if (bid < 1024) {
    stats_body<N_, 4, false>(pg_t, pg_t, stpg, bid & 31, bid >> 5, Ks);
  } else {
    int pid = bid - 1024;
    stats_body<NP_, 1, true>(pp_t, pp_t, stpp, pid & 7, pid >> 3, Ks);
  }
}

// ---------------- merged stats merge: A2 = REF*log2e - log2(sum of partial Z)
__global__ __launch_bounds__(256) void k_merge_all(
    const float* __restrict__ stpg, float* __restrict__ stg,
    const float* __restrict__ stpp, float* __restrict__ stp2) {
  int i = blockIdx.x * 256 + threadIdx.x;
  if (i < 8 * N_) {
    const float* p = stpg + (size_t)i * 4;
    float Z = p[0] + p[1] + p[2] + p[3];
    stg[i] = REFL2_ - __log2f(Z);
  } else {
    int j = i - 8 * N_;
    if (j < 72 * NP_) stp2[j] = REFL2_ - __log2f(stpp[j]);
  }
}

// ---------------- PV body: out[c,m] (+)= sum_{n in chunk} v[c,n]exp2(A2_n - e*L2E)
template <int NT, int NSPLIT, bool PATCH>
__device__ __attribute__((always_inline)) void pv_body(
    const f16* __restrict__ qT_all, const f16* __restrict__ kT_all,
    const f16* __restrict__ vN_all, const float* __restrict__ st_all,
    float* __restrict__ out_all, int bx, int by,
    float* As2, uint4* Qs, uint4* Vs, uint2* wt2) {
  constexpr int CH = NT / NSPLIT;   // 1024 both configs
  constexpr int NTI = CH / 64;      // 16
  int tid = threadIdx.x, wave = tid >> 6, lane = tid & 63, g = lane >> 4, lm = lane & 15;
  int ns = by % NSPLIT, z = by / NSPLIT;
  const f16 *qT, *kT, *vN;
  float* op;
  if (PATCH) {
    int X = z / 18, b = (z / 9) % 2, p = z % 9;
    qT = qT_all + ((size_t)(b * 9 + p)) * NT * 64;
    op = out_all + ((size_t)((p * 2 + b) * C4_ + X * 48)) * NT;
  } else {
    int X = z >> 1, b = z & 1;
    qT = qT_all + (size_t)b * NT * 64;
    op = out_all + ((size_t)(b * C4_ + X * 48)) * NT;
  }
  kT = kT_all + (size_t)z * NT * 64;
  vN = vN_all + (size_t)z * 48 * NT;
  const float* st = st_all + (size_t)z * NT + ns * CH;
  ((float4*)As2)[tid] = ((const float4*)st)[tid];  // CH/4 == 256
  int mwa = bx * 128 + wave * 16;  // tile a; tile b = +64
  int mwb = mwa + 64;
  f16x8 bk0a = *(const f16x8*)(kT + (size_t)(mwa + lm) * 64 + g * 8);
  f16x8 bk1a = *(const f16x8*)(kT + (size_t)(mwa + lm) * 64 + 32 + g * 8);
  f16x8 bk0b = *(const f16x8*)(kT + (size_t)(mwb + lm) * 64 + g * 8);
  f16x8 bk1b = *(const f16x8*)(kT + (size_t)(mwb + lm) * 64 + 32 + g * 8);
  const int s0r = tid >> 3, s0c = (tid & 7) * 8;
  const int sw0 = tid ^ ((tid >> 3) & 7);
  const int sw1 = (tid + 256) ^ (((tid + 256) >> 3) & 7);
  const int swl = lm & 7;
  const int c0i = g ^ swl, c1i = (4 + g) ^ swl;
  int t_beg = ns * NTI;
  {
    const f16* qsrc = qT + (size_t)t_beg * 64 * 64;
    Qs[sw0] = *(const uint4*)(qsrc + (size_t)s0r * 64 + s0c);
    Qs[sw1] = *(const uint4*)(qsrc + (size_t)(s0r + 32) * 64 + s0c);
    Vs[sw0] = *(const uint4*)(vN + (size_t)s0r * NT + t_beg * 64 + s0c);
    if (tid < 128)
      Vs[sw1] = *(const uint4*)(vN + (size_t)(s0r + 32) * NT + t_beg * 64 + s0c);
  }
  __syncthreads();
  f32x4 oa0 = {0.f, 0.f, 0.f, 0.f}, oa1 = {0.f, 0.f, 0.f, 0.f}, oa2 = {0.f, 0.f, 0.f, 0.f};
  f32x4 ob0 = {0.f, 0.f, 0.f, 0.f}, ob1 = {0.f, 0.f, 0.f, 0.f}, ob2 = {0.f, 0.f, 0.f, 0.f};
  int wbufa = wave * 512;        // uint2 units, tile a
  int wbufb = wave * 512 + 256;  // tile b
  int rba = wbufa + lm * 16;
  int rbb = wbufb + lm * 16;
  for (int nt = 0; nt < NTI; ++nt) {
    bool pf = (nt + 1 < NTI);
    uint4 q0v, q1v, v0v, v1v;
    if (pf) {  // issue early; latency hides under compute
      int tn = t_beg + nt + 1;
      const f16* qsrc = qT + (size_t)tn * 64 * 64;
      q0v = *(const uint4*)(qsrc + (size_t)s0r * 64 + s0c);
      q1v = *(const uint4*)(qsrc + (size_t)(s0r + 32) * 64 + s0c);
      v0v = *(const uint4*)(vN + (size_t)s0r * NT + tn * 64 + s0c);
      if (tid < 128)
        v1v = *(const uint4*)(vN + (size_t)(s0r + 32) * NT + tn * 64 + s0c);
    }
    // e for BOTH m-tiles (16 independent MFMA)
    f32x4 ea[4], eb[4];
    __builtin_amdgcn_s_setprio(1);
#pragma unroll
    for (int nf = 0; nf < 4; ++nf) {
      f16x8 a0 = __builtin_bit_cast(f16x8, Qs[(16 * nf + lm) * 8 + c0i]);
      f16x8 a1 = __builtin_bit_cast(f16x8, Qs[(16 * nf + lm) * 8 + c1i]);
      f32x4 ta = {0.f, 0.f, 0.f, 0.f};
      ta = MFMA32(a0, bk0a, ta);
      ta = MFMA32(a1, bk1a, ta);
      ea[nf] = ta;
      f32x4 tb = {0.f, 0.f, 0.f, 0.f};
      tb = MFMA32(a0, bk0b, tb);
      tb = MFMA32(a1, bk1b, tb);
      eb[nf] = tb;
    }
    __builtin_amdgcn_s_setprio(0);
    // exp + pack + write both tiles (A2 loads shared, from LDS)
#pragma unroll
    for (int nf = 0; nf < 4; ++nf) {
      float4 a4 = *(const float4*)&As2[nt * 64 + nf * 16 + g * 4];
      float wa0 = fast_exp2(fmaf(ea[nf][0], -L2E_, a4.x));
      float wa1 = fast_exp2(fmaf(ea[nf][1], -L2E_, a4.y));
      float wa2 = fast_exp2(fmaf(ea[nf][2], -L2E_, a4.z));
      float wa3 = fast_exp2(fmaf(ea[nf][3], -L2E_, a4.w));
      float wb0 = fast_exp2(fmaf(eb[nf][0], -L2E_, a4.x));
      float wb1 = fast_exp2(fmaf(eb[nf][1], -L2E_, a4.y));
      float wb2 = fast_exp2(fmaf(eb[nf][2], -L2E_, a4.z));
      float wb3 = fast_exp2(fmaf(eb[nf][3], -L2E_, a4.w));
      unsigned la = __builtin_bit_cast(unsigned, __builtin_amdgcn_cvt_pkrtz(wa0, wa1));
      unsigned ha = __builtin_bit_cast(unsigned, __builtin_amdgcn_cvt_pkrtz(wa2, wa3));
      unsigned lb = __builtin_bit_cast(unsigned, __builtin_amdgcn_cvt_pkrtz(wb0, wb1));
      unsigned hb = __builtin_bit_cast(unsigned, __builtin_amdgcn_cvt_pkrtz(wb2, wb3));
      int s = 2 * nf + (g >> 1);
      int so = ((s ^ swl) * 2) + (g & 1);
      wt2[wbufa + lm * 16 + so] = make_uint2(la, ha);
      wt2[wbufb + lm * 16 + so] = make_uint2(lb, hb);
    }
    __builtin_amdgcn_sched_barrier(0);  // bounce reads after writes
    f16x8 bw0a = __builtin_bit_cast(f16x8, *(const uint4*)&wt2[rba + c0i * 2]);
    f16x8 bw1a = __builtin_bit_cast(f16x8, *(const uint4*)&wt2[rba + c1i * 2]);
    f16x8 bw0b = __builtin_bit_cast(f16x8, *(const uint4*)&wt2[rbb + c0i * 2]);
    f16x8 bw1b = __builtin_bit_cast(f16x8, *(const uint4*)&wt2[rbb + c1i * 2]);
    __builtin_amdgcn_s_setprio(1);
#pragma unroll
    for (int cf = 0; cf < 3; ++cf) {
      f16x8 av0 = __builtin_bit_cast(f16x8, Vs[(16 * cf + lm) * 8 + c0i]);
      f16x8 av1 = __builtin_bit_cast(f16x8, Vs[(16 * cf + lm) * 8 + c1i]);
      if (cf == 0) {
        oa0 = MFMA32(av0, bw0a, oa0); oa0 = MFMA32(av1, bw1a, oa0);
        ob0 = MFMA32(av0, bw0b, ob0); ob0 = MFMA32(av1, bw1b, ob0);
      }
      if (cf == 1) {
        oa1 = MFMA32(av0, bw0a, oa1); oa1 = MFMA32(av1, bw1a, oa1);
        ob1 = MFMA32(av0, bw0b, ob1); ob1 = MFMA32(av1, bw1b, ob1);
      }
      if (cf == 2) {
        oa2 = MFMA32(av0, bw0a, oa2); oa2 = MFMA32(av1, bw1a, oa2);
        ob2 = MFMA32(av0, bw0b, ob2); ob2 = MFMA32(av1, bw1b, ob2);
      }
    }
    __builtin_amdgcn_s_setprio(0);
    __syncthreads();  // all reads of Qs/Vs done
    if (pf) {
      Qs[sw0] = q0v;
      Qs[sw1] = q1v;
      Vs[sw0] = v0v;
      if (tid < 128) Vs[sw1] = v1v;
    }
    __syncthreads();  // writes visible (also orders wt2 across iters)
  }
  if (NSPLIT == 1) {
#pragma unroll
    for (int r = 0; r < 4; ++r) {
      op[(size_t)(0 + 4 * g + r) * NT + mwa + lm] = oa0[r];
      op[(size_t)(16 + 4 * g + r) * NT + mwa + lm] = oa1[r];
      op[(size_t)(32 + 4 * g + r) * NT + mwa + lm] = oa2[r];
      op[(size_t)(0 + 4 * g + r) * NT + mwb + lm] = ob0[r];
      op[(size_t)(16 + 4 * g + r) * NT + mwb + lm] = ob1[r];
      op[(size_t)(32 + 4 * g + r) * NT + mwb + lm] = ob2[r];
    }
  } else {
#pragma unroll
    for (int r = 0; r < 4; ++r) {
      atomicAdd(&op[(size_t)(0 + 4 * g + r) * NT + mwa + lm], oa0[r]);
      atomicAdd(&op[(size_t)(16 + 4 * g + r) * NT + mwa + lm], oa1[r]);
      atomicAdd(&op[(size_t)(32 + 4 * g + r) * NT + mwa + lm], oa2[r]);
      atomicAdd(&op[(size_t)(0 + 4 * g + r) * NT + mwb + lm], ob0[r]);
      atomicAdd(&op[(size_t)(16 + 4 * g + r) * NT + mwb + lm], ob1[r]);
      atomicAdd(&op[(size_t)(32 + 4 * g + r) * NT + mwb + lm], ob2[r]);
    }
  }
}

// ---------------- merged PV: blocks [0,1024) global, [1024,1600) patch
__global__ __launch_bounds__(256, 4) void k_pv_all(
    const f16* __restrict__ pg_t, const f16* __restrict__ pg_n,
    const float* __restrict__ statsg, float* __restrict__ cat,
    const f16* __restrict__ pp_t, const f16* __restrict__ pp_n,
    const float* __restrict__ statsp, float* __restrict__ pcat) {
  __shared__ float As2[1024];
  __shared__ uint4 Qs[512];
  __shared__ uint4 Vs[384];
  __shared__ uint2 wt2[2048];
  int bid = blockIdx.x;
  if (bid < 1024) {
    pv_body<N_, 4, false>(pg_t, pg_t, pg_n, statsg, cat, bid & 31, bid >> 5,
                          As2, Qs, Vs, wt2);
  } else {
    int pid = bid - 1024;
    pv_body<NP_, 1, true>(pp_t, pp_t, pp_n, statsp, pcat, pid & 7, pid >> 3,
                          As2, Qs, Vs, wt2);
  }
}

// ---------------- LDS-tiled fuse: blocks [0,128) global, [128,416) patch
__global__ __launch_bounds__(256) void k_fuse2(
    const float* __restrict__ cat, const float* __restrict__ fw,
    const float* __restrict__ fb, const float* __restrict__ fg,
    const float* __restrict__ fbb, const float* __restrict__ fm,
    const float* __restrict__ fv, const float* __restrict__ gamma_all,
    const float* __restrict__ input, float* __restrict__ comb,
    const float* __restrict__ pcat, const float* __restrict__ pfw,
    const float* __restrict__ pfb, const float* __restrict__ pfg,
    const float* __restrict__ pfbb, const float* __restrict__ pfm,
    const float* __restrict__ pfv, const float* __restrict__ gamma_p) {
  __shared__ float panel[192 * 64];  // 48 KB
  int tid = threadIdx.x;
  int bid = blockIdx.x;
  int n = tid & 63, og = tid >> 6;  // wave-uniform og (4 groups of 12 outputs)
  if (bid < 128) {
    int b = bid >> 6;          // 64 blocks per batch
    int n0 = (bid & 63) * 64;
    const float* src = cat + (size_t)b * C4_ * N_ + n0;
    for (int i = tid; i < 3072; i += 256) {
      int c = i >> 4, j = (i & 15) * 4;
      *(float4*)&panel[c * 64 + j] = *(const float4*)(src + (size_t)c * N_ + j);
    }
    __syncthreads();
    float acc[12] = {0.f, 0.f, 0.f, 0.f, 0.f, 0.f, 0.f, 0.f, 0.f, 0.f, 0.f, 0.f};
    const float* wbase = fw + (size_t)(og * 12) * C4_;
    for (int c = 0; c < C4_; ++c) {
      float xv = panel[c * 64 + n];
#pragma unroll
      for (int k = 0; k < 12; ++k)
        acc[k] = fmaf(wbase[(size_t)k * C4_ + c], xv, acc[k]);
    }
    float ga = gamma_all[0];
#pragma unroll
    for (int k = 0; k < 12; ++k) {
      int o = og * 12 + k;
      float scale = fg[o] * rsqrtf(fv[o] + EPS_);
      float y = (acc[k] + fb[o] - fm[o]) * scale + fbb[o];
      size_t oi = ((size_t)(b * C_ + o)) * N_ + n0 + n;
      atomicAdd(&comb[oi], input[oi] + ga * fmaxf(y, 0.f));
    }
  } else {
    int pid = bid - 128;       // 288 blocks: 16 per (p,b)-slice
    int slice = pid >> 4;      // = p*2 + b
    int t0 = (pid & 15) * 64;
    int p = slice >> 1, b = slice & 1;
    const float* src = pcat + (size_t)slice * C4_ * NP_ + t0;
    for (int i = tid; i < 3072; i += 256) {
      int c = i >> 4, j = (i & 15) * 4;
      *(float4*)&panel[c * 64 + j] = *(const float4*)(src + (size_t)c * NP_ + j);
    }
    __syncthreads();
    float acc[12] = {0.f, 0.f, 0.f, 0.f, 0.f, 0.f, 0.f, 0.f, 0.f, 0.f, 0.f, 0.f};
    const float* wbase = pfw + ((size_t)p * C_ + og * 12) * C4_;
    for (int c = 0; c < C4_; ++c) {
      float xv = panel[c * 64 + n];
#pragma unroll
      for (int k = 0; k < 12; ++k)
        acc[k] = fmaf(wbase[(size_t)k * C4_ + c], xv, acc[k]);
    }
    int t = t0 + n;
    int r0 = (p / 3) * 16, c0w = (p % 3) * 16;
    int h = r0 + (t >> 5), w = c0w + (t & 31);
    float gp = 0.5f * gamma_p[p];
#pragma unroll
    for (int k = 0; k < 12; ++k) {
      int o = og * 12 + k;
      int po = p * C_ + o;
      float scale = pfg[po] * rsqrtf(pfv[po] + EPS_);
      float y = (acc[k] + pfb[po] - pfm[po]) * scale + pfbb[po];
      atomicAdd(&comb[((size_t)(b * C_ + o)) * N_ + h * 64 + w], gp * fmaxf(y, 0.f));
    }
  }
}

// ---------------- 3x3 conv (SAME) + BN + relu; fp32 comb -> fp16 LDS staging
__global__ __launch_bounds__(256) void k_conv2(
    const float* __restrict__ comb, const float* __restrict__ cw,
    const float* __restrict__ cb, const float* __restrict__ cg,
    const float* __restrict__ cbb, const float* __restrict__ cm,
    const float* __restrict__ cv, float* __restrict__ out) {
  __shared__ f16 inh[48 * 6 * 64];  // 36 KB: [c][r][w] fp16
  int tid = threadIdx.x;
  int h0 = blockIdx.x * 4, ocg = blockIdx.y, b = blockIdx.z;
  // stage 48ch x 6 rows x 64 cols: load fp32 float4, convert, store f16x4
  for (int i = tid; i < 4608; i += 256) {  // 4608 = 48*6*16 quads
    int c = i / 96;
    int rem = i - c * 96;
    int r = rem >> 4, u = rem & 15;
    int hh = h0 - 1 + r;
    float4 val = make_float4(0.f, 0.f, 0.f, 0.f);
    if (hh >= 0 && hh < H_)
      val = *(const float4*)(comb + (((size_t)(b * C_ + c) * H_ + hh) * W_ + u * 4));
    f16* dst = &inh[(c * 6 + r) * 64 + u * 4];
    dst[0] = (f16)val.x; dst[1] = (f16)val.y;
    dst[2] = (f16)val.z; dst[3] = (f16)val.w;
  }
  __syncthreads();
  int w = tid & 63, dh = tid >> 6;
  float acc[6] = {0.f, 0.f, 0.f, 0.f, 0.f, 0.f};
  int wm = w > 0 ? w - 1 : 0;
  int wp = w < 63 ? w + 1 : 63;
  for (int c = 0; c < 48; ++c) {
    float v[9];
#pragma unroll
    for (int r = 0; r < 3; ++r) {
      const f16* row = &inh[(size_t)(c * 6 + dh + r) * 64];
      float lf = (float)row[wm];
      float md = (float)row[w];
      float rt = (float)row[wp];
      v[r * 3 + 0] = (w > 0) ? lf : 0.f;
      v[r * 3 + 1] = md;
      v[r * 3 + 2] = (w < 63) ? rt : 0.f;
    }
#pragma unroll
    for (int j = 0; j < 6; ++j) {
      const float* wr = cw + (size_t)((ocg * 6 + j) * 48 + c) * 9;
#pragma unroll
      for (int k = 0; k < 9; ++k) acc[j] = fmaf(v[k], wr[k], acc[j]);
    }
  }
#pragma unroll
  for (int j = 0; j < 6; ++j) {
    int o = ocg * 6 + j;
    float scale = cg[o] * rsqrtf(cv[o] + EPS_);
    float y = (acc[j] + cb[o] - cm[o]) * scale + cbb[o];
    out[(size_t)(b * C_ + o) * N_ + (h0 + dh) * 64 + w] = fmaxf(y, 0.f);
  }
}

extern "C" void kernel_launch(void* const* d_in, const int* in_sizes, int n_in,
                              void* d_out, int out_size, void* d_ws, size_t ws_size,
                              hipStream_t stream) {
  (void)in_sizes; (void)n_in; (void)out_size; (void)ws_size;
  const float* x[4];
  const float* Wall[4];
  const float* Wp[4];
  for (int i = 0; i < 4; ++i) {
    x[i] = (const float*)d_in[i];
    Wall[i] = (const float*)d_in[4 + i];
    Wp[i] = (const float*)d_in[8 + i];
  }
  const float* fuse_w = (const float*)d_in[12];
  const float* fuse_b = (const float*)d_in[13];
  const float* fuse_g = (const float*)d_in[14];
  const float* fuse_bb = (const float*)d_in[15];
  const float* fuse_m = (const float*)d_in[16];
  const float* fuse_v = (const float*)d_in[17];
  const float* fuseP_w = (const float*)d_in[18];
  const float* fuseP_b = (const float*)d_in[19];
  const float* fuseP_g = (const float*)d_in[20];
  const float* fuseP_bb = (const float*)d_in[21];
  const float* fuseP_m = (const float*)d_in[22];
  const float* fuseP_v = (const float*)d_in[23];
  const float* gamma_all = (const float*)d_in[24];
  const float* gamma_p = (const float*)d_in[25];
  const float* out_w = (const float*)d_in[26];
  const float* out_b = (const float*)d_in[27];
  const float* out_g = (const float*)d_in[28];
  const float* out_bb = (const float*)d_in[29];
  const float* out_m = (const float*)d_in[30];
  const float* out_v = (const float*)d_in[31];

  char* base = (char*)d_ws;
  size_t off = 0;
  auto carve = [&](size_t bytes) {
    char* p = base + off;
    off += (bytes + 255) & ~(size_t)255;
    return p;
  };
  f16* projg_n = (f16*)carve((size_t)8 * 48 * N_ * 2);
  f16* projg_t = (f16*)carve((size_t)8 * N_ * 64 * 2);
  f16* projp_n = (f16*)carve((size_t)72 * 48 * NP_ * 2);
  f16* projp_t = (f16*)carve((size_t)72 * NP_ * 64 * 2);
  float* stpg = (float*)carve((size_t)8 * N_ * 4 * 4);
  float* stpp = (float*)carve((size_t)72 * NP_ * 4);
  float* statsg = (float*)carve((size_t)8 * N_ * 4);
  float* statsp = (float*)carve((size_t)72 * NP_ * 4);
  float* cat = (float*)carve((size_t)B_ * C4_ * N_ * 4);
  float* pcat = (float*)carve((size_t)9 * B_ * C4_ * NP_ * 4);
  float* comb = (float*)carve((size_t)B_ * C_ * N_ * 4);

  dim3 blk(256);

  (void)hipMemsetAsync(cat, 0, (size_t)B_ * C4_ * N_ * sizeof(float), stream);
  (void)hipMemsetAsync(comb, 0, (size_t)B_ * C_ * N_ * sizeof(float), stream);
  k_proj_all<<<dim3(416), blk, 0, stream>>>(
      x[0], x[1], x[2], x[3], Wall[0], Wall[1], Wall[2], Wall[3],
      Wp[0], Wp[1], Wp[2], Wp[3], projg_n, projg_t, projp_n, projp_t);

  k_stats_all<<<dim3(1600), blk, 0, stream>>>(projg_t, stpg, projp_t, stpp);
  k_merge_all<<<dim3((8 * N_ + 72 * NP_ + 255) / 256), blk, 0, stream>>>(
      stpg, statsg, stpp, statsp);

  k_pv_all<<<dim3(1600), blk, 0, stream>>>(
      projg_t, projg_n, statsg, cat, projp_t, projp_n, statsp, pcat);

  k_fuse2<<<dim3(416), blk, 0, stream>>>(
      cat, fuse_w, fuse_b, fuse_g, fuse_bb, fuse_m, fuse_v, gamma_all, x[0], comb,
      pcat, fuseP_w, fuseP_b, fuseP_g, fuseP_bb, fuseP_m, fuseP_v, gamma_p);
  k_conv2<<<dim3(16, 8, 2), blk, 0, stream>>>(
      comb, out_w, out_b, out_g, out_bb, out_m, out_v, (float*)d_out);
}

// Round 20
// 232.625 us; speedup vs baseline: 1.0121x; 1.0121x over previous
//
#include <hip/hip_runtime.h>
#include <math.h>

typedef _Float16 f16;
typedef f16 f16x8 __attribute__((ext_vector_type(8)));
typedef float f32x4 __attribute__((ext_vector_type(4)));

namespace {
constexpr int B_ = 2, C_ = 48, H_ = 64, W_ = 64;
constexpr int N_ = H_ * W_;    // 4096
constexpr int NP_ = 1024;      // 32*32
constexpr int C4_ = 4 * C_;    // 192
constexpr float EPS_ = 1e-5f;
constexpr float L2E_ = 1.44269504f;
constexpr float REFL2_ = -25.0f * 1.44269504f;  // REF * log2(e), REF = -25
}

#define MFMA32(a, b, c) __builtin_amdgcn_mfma_f32_16x16x32_f16((a), (b), (c), 0, 0, 0)

__device__ inline float fast_exp2(float x) {
#if __has_builtin(__builtin_amdgcn_exp2f)
  return __builtin_amdgcn_exp2f(x);
#else
  float r;
  asm("v_exp_f32 %0, %1" : "=v"(r) : "v"(x));
  return r;
#endif
}

// ---------------- projection body (shared by global/patch)
__device__ __attribute__((always_inline)) void proj_body(
    const float* __restrict__ xb, const float* __restrict__ Ws,
    f16* __restrict__ pnb, size_t pn_stride, f16* __restrict__ ptb) {
  float acc[48];
#pragma unroll
  for (int d = 0; d < 48; ++d) acc[d] = 0.f;
  for (int c0 = 0; c0 < 48; c0 += 4) {
    float xv0 = xb[(size_t)(c0 + 0) * 4096];
    float xv1 = xb[(size_t)(c0 + 1) * 4096];
    float xv2 = xb[(size_t)(c0 + 2) * 4096];
    float xv3 = xb[(size_t)(c0 + 3) * 4096];
#pragma unroll
    for (int d = 0; d < 48; ++d) {
      const float4 wv = *(const float4*)&Ws[d * 48 + c0];
      acc[d] = fmaf(wv.x, xv0, fmaf(wv.y, xv1, fmaf(wv.z, xv2, fmaf(wv.w, xv3, acc[d]))));
    }
  }
#pragma unroll
  for (int d = 0; d < 48; ++d) pnb[(size_t)d * pn_stride] = (f16)acc[d];
#pragma unroll
  for (int s = 0; s < 6; ++s) {
    f16x8 v;
#pragma unroll
    for (int j = 0; j < 8; ++j) v[j] = (f16)acc[s * 8 + j];
    *(f16x8*)(ptb + s * 8) = v;
  }
  f16x8 zv = {0, 0, 0, 0, 0, 0, 0, 0};
  *(f16x8*)(ptb + 48) = zv;
  *(f16x8*)(ptb + 56) = zv;
}

// ---------------- merged projections: blocks [0,128) global, [128,416) patch
__global__ __launch_bounds__(256) void k_proj_all(
    const float* __restrict__ x0, const float* __restrict__ x1,
    const float* __restrict__ x2, const float* __restrict__ x3,
    const float* __restrict__ w0, const float* __restrict__ w1,
    const float* __restrict__ w2, const float* __restrict__ w3,
    const float* __restrict__ wp0, const float* __restrict__ wp1,
    const float* __restrict__ wp2, const float* __restrict__ wp3,
    f16* __restrict__ pgn, f16* __restrict__ pgt,
    f16* __restrict__ ppn, f16* __restrict__ ppt) {
  __shared__ float Ws[48 * 48];
  int tid = threadIdx.x;
  int bid = blockIdx.x;
  if (bid < 128) {
    int bx = bid & 15, b = (bid >> 4) & 1, X = bid >> 5;
    const float* xp = X == 0 ? x0 : X == 1 ? x1 : X == 2 ? x2 : x3;
    const float* wp = X == 0 ? w0 : X == 1 ? w1 : X == 2 ? w2 : w3;
    for (int i = tid; i < 2304; i += 256) Ws[i] = wp[i];
    __syncthreads();
    int n = bx * 256 + tid;
    int z2 = X * 2 + b;
    proj_body(xp + (size_t)b * 48 * 4096 + n, Ws,
              pgn + ((size_t)z2 * 48) * 4096 + n, 4096,
              pgt + ((size_t)z2 * 4096 + n) * 64);
  } else {
    int pid = bid - 128;
    int bx = pid & 3;
    int rest = pid >> 2;
    int p = rest % 9;
    int zb = rest / 9;
    int X = zb >> 1, b = zb & 1;
    const float* xp = X == 0 ? x0 : X == 1 ? x1 : X == 2 ? x2 : x3;
    const float* wp = (X == 0 ? wp0 : X == 1 ? wp1 : X == 2 ? wp2 : wp3) + (size_t)p * 2304;
    for (int i = tid; i < 2304; i += 256) Ws[i] = wp[i];
    __syncthreads();
    int t = bx * 256 + tid;
    int r0 = (p / 3) * 16, c0w = (p % 3) * 16;
    int rr = r0 + (t >> 5), cc = c0w + (t & 31);
    int z9 = (X * 2 + b) * 9 + p;
    proj_body(xp + (size_t)b * 48 * 4096 + rr * 64 + cc, Ws,
              ppn + ((size_t)z9 * 48) * 1024 + t, 1024,
              ppt + ((size_t)z9 * 1024 + t) * 64);
  }
}

// ---------------- stats body: partial Z[n] = sum_{m in chunk} exp(REF - e[n,m])
template <int NT, int NSPLIT, bool PATCH>
__device__ __attribute__((always_inline)) void stats_body(
    const f16* __restrict__ qT_all, const f16* __restrict__ kT_all,
    float* __restrict__ stp, int bx, int by, uint4* Ks) {
  constexpr int MTI = (NT / NSPLIT) / 64;
  int tid = threadIdx.x, wave = tid >> 6, lane = tid & 63, g = lane >> 4, lm = lane & 15;
  int ms = by % NSPLIT, z = by / NSPLIT;
  const f16* qT;
  if (PATCH) {
    int b = (z / 9) % 2, p = z % 9;
    qT = qT_all + ((size_t)(b * 9 + p)) * NT * 64;
  } else {
    int b = z & 1;
    qT = qT_all + (size_t)b * NT * 64;
  }
  const f16* kT = kT_all + (size_t)z * NT * 64;
  int n0 = bx * 128 + wave * 16;  // tile a; tile b = n0 + 64
  f16x8 aq0a = *(const f16x8*)(qT + (size_t)(n0 + lm) * 64 + g * 8);
  f16x8 aq1a = *(const f16x8*)(qT + (size_t)(n0 + lm) * 64 + 32 + g * 8);
  f16x8 aq0b = *(const f16x8*)(qT + (size_t)(n0 + 64 + lm) * 64 + g * 8);
  f16x8 aq1b = *(const f16x8*)(qT + (size_t)(n0 + 64 + lm) * 64 + 32 + g * 8);
  const int s0r = tid >> 3, s0c = (tid & 7) * 8;
  const int sw0 = tid ^ ((tid >> 3) & 7);
  const int sw1 = (tid + 256) ^ (((tid + 256) >> 3) & 7);
  const int swl = lm & 7;
  const int c0i = g ^ swl, c1i = (4 + g) ^ swl;
  int t_beg = ms * MTI;
  {
    const f16* src = kT + (size_t)t_beg * 64 * 64;
    Ks[sw0] = *(const uint4*)(src + (size_t)s0r * 64 + s0c);
    Ks[sw1] = *(const uint4*)(src + (size_t)(s0r + 32) * 64 + s0c);
  }
  __syncthreads();
  float zsa[4] = {0.f, 0.f, 0.f, 0.f};
  float zsb[4] = {0.f, 0.f, 0.f, 0.f};
  for (int mt = 0; mt < MTI; ++mt) {
    int cur = mt & 1;
    bool pf = (mt + 1 < MTI);
    uint4 k0v, k1v;
    if (pf) {
      const f16* src = kT + (size_t)(t_beg + mt + 1) * 64 * 64;
      k0v = *(const uint4*)(src + (size_t)s0r * 64 + s0c);
      k1v = *(const uint4*)(src + (size_t)(s0r + 32) * 64 + s0c);
    }
    uint4* kb = Ks + cur * 512;
    __builtin_amdgcn_s_setprio(1);
#pragma unroll
    for (int mf = 0; mf < 4; ++mf) {
      f16x8 b0 = __builtin_bit_cast(f16x8, kb[(16 * mf + lm) * 8 + c0i]);
      f16x8 b1 = __builtin_bit_cast(f16x8, kb[(16 * mf + lm) * 8 + c1i]);
      f32x4 ea = {0.f, 0.f, 0.f, 0.f};
      ea = MFMA32(aq0a, b0, ea);
      ea = MFMA32(aq1a, b1, ea);
      f32x4 eb = {0.f, 0.f, 0.f, 0.f};
      eb = MFMA32(aq0b, b0, eb);
      eb = MFMA32(aq1b, b1, eb);
#pragma unroll
      for (int r = 0; r < 4; ++r) {
        zsa[r] += fast_exp2(fmaf(ea[r], -L2E_, REFL2_));
        zsb[r] += fast_exp2(fmaf(eb[r], -L2E_, REFL2_));
      }
    }
    __builtin_amdgcn_s_setprio(0);
    if (pf) {
      uint4* kn = Ks + (cur ^ 1) * 512;
      kn[sw0] = k0v;
      kn[sw1] = k1v;
    }
    __syncthreads();
  }
#pragma unroll
  for (int mask = 1; mask < 16; mask <<= 1) {
#pragma unroll
    for (int r = 0; r < 4; ++r) {
      zsa[r] += __shfl_xor(zsa[r], mask, 64);
      zsb[r] += __shfl_xor(zsb[r], mask, 64);
    }
  }
  if (lm == 0) {
#pragma unroll
    for (int r = 0; r < 4; ++r) {
      stp[((size_t)z * NT + n0 + 4 * g + r) * NSPLIT + ms] = zsa[r];
      stp[((size_t)z * NT + n0 + 64 + 4 * g + r) * NSPLIT + ms] = zsb[r];
    }
  }
}

// ---------------- merged stats: blocks [0,1024) global, [1024,1600) patch
__global__ __launch_bounds__(256, 6) void k_stats_all(
    const f16* __restrict__ pg_t, float* __restrict__ stpg,
    const f16* __restrict__ pp_t, float* __restrict__ stpp) {
  __shared__ uint4 Ks[2 * 512];
  int bid = blockIdx.x;
  if (bid < 1024) {
    stats_body<N_, 4, false>(pg_t, pg_t, stpg, bid & 31, bid >> 5, Ks);
  } else {
    int pid = bid - 1024;
    stats_body<NP_, 1, true>(pp_t, pp_t, stpp, pid & 7, pid >> 3, Ks);
  }
}

// ---------------- merged stats merge: A2 = REF*log2e - log2(sum of partial Z)
__global__ __launch_bounds__(256) void k_merge_all(
    const float* __restrict__ stpg, float* __restrict__ stg,
    const float* __restrict__ stpp, float* __restrict__ stp2) {
  int i = blockIdx.x * 256 + threadIdx.x;
  if (i < 8 * N_) {
    const float* p = stpg + (size_t)i * 4;
    float Z = p[0] + p[1] + p[2] + p[3];
    stg[i] = REFL2_ - __log2f(Z);
  } else {
    int j = i - 8 * N_;
    if (j < 72 * NP_) stp2[j] = REFL2_ - __log2f(stpp[j]);
  }
}

// ---------------- PV body: out[c,m] (+)= sum_{n in chunk} v[c,n]exp2(A2_n - e*L2E)
template <int NT, int NSPLIT, bool PATCH>
__device__ __attribute__((always_inline)) void pv_body(
    const f16* __restrict__ qT_all, const f16* __restrict__ kT_all,
    const f16* __restrict__ vN_all, const float* __restrict__ st_all,
    float* __restrict__ out_all, int bx, int by,
    float* As2, uint4* Qs, uint4* Vs, uint2* wt2) {
  constexpr int CH = NT / NSPLIT;   // 1024 both configs
  constexpr int NTI = CH / 64;      // 16
  int tid = threadIdx.x, wave = tid >> 6, lane = tid & 63, g = lane >> 4, lm = lane & 15;
  int ns = by % NSPLIT, z = by / NSPLIT;
  const f16 *qT, *kT, *vN;
  float* op;
  if (PATCH) {
    int X = z / 18, b = (z / 9) % 2, p = z % 9;
    qT = qT_all + ((size_t)(b * 9 + p)) * NT * 64;
    op = out_all + ((size_t)((p * 2 + b) * C4_ + X * 48)) * NT;
  } else {
    int X = z >> 1, b = z & 1;
    qT = qT_all + (size_t)b * NT * 64;
    op = out_all + ((size_t)(b * C4_ + X * 48)) * NT;
  }
  kT = kT_all + (size_t)z * NT * 64;
  vN = vN_all + (size_t)z * 48 * NT;
  const float* st = st_all + (size_t)z * NT + ns * CH;
  ((float4*)As2)[tid] = ((const float4*)st)[tid];  // CH/4 == 256
  int mwa = bx * 128 + wave * 16;  // tile a; tile b = +64
  int mwb = mwa + 64;
  f16x8 bk0a = *(const f16x8*)(kT + (size_t)(mwa + lm) * 64 + g * 8);
  f16x8 bk1a = *(const f16x8*)(kT + (size_t)(mwa + lm) * 64 + 32 + g * 8);
  f16x8 bk0b = *(const f16x8*)(kT + (size_t)(mwb + lm) * 64 + g * 8);
  f16x8 bk1b = *(const f16x8*)(kT + (size_t)(mwb + lm) * 64 + 32 + g * 8);
  const int s0r = tid >> 3, s0c = (tid & 7) * 8;
  const int sw0 = tid ^ ((tid >> 3) & 7);
  const int sw1 = (tid + 256) ^ (((tid + 256) >> 3) & 7);
  const int swl = lm & 7;
  const int c0i = g ^ swl, c1i = (4 + g) ^ swl;
  int t_beg = ns * NTI;
  {
    const f16* qsrc = qT + (size_t)t_beg * 64 * 64;
    Qs[sw0] = *(const uint4*)(qsrc + (size_t)s0r * 64 + s0c);
    Qs[sw1] = *(const uint4*)(qsrc + (size_t)(s0r + 32) * 64 + s0c);
    Vs[sw0] = *(const uint4*)(vN + (size_t)s0r * NT + t_beg * 64 + s0c);
    if (tid < 128)
      Vs[sw1] = *(const uint4*)(vN + (size_t)(s0r + 32) * NT + t_beg * 64 + s0c);
  }
  __syncthreads();
  f32x4 oa0 = {0.f, 0.f, 0.f, 0.f}, oa1 = {0.f, 0.f, 0.f, 0.f}, oa2 = {0.f, 0.f, 0.f, 0.f};
  f32x4 ob0 = {0.f, 0.f, 0.f, 0.f}, ob1 = {0.f, 0.f, 0.f, 0.f}, ob2 = {0.f, 0.f, 0.f, 0.f};
  int wbufa = wave * 512;        // uint2 units, tile a
  int wbufb = wave * 512 + 256;  // tile b
  int rba = wbufa + lm * 16;
  int rbb = wbufb + lm * 16;
  for (int nt = 0; nt < NTI; ++nt) {
    bool pf = (nt + 1 < NTI);
    uint4 q0v, q1v, v0v, v1v;
    if (pf) {  // issue early; latency hides under compute
      int tn = t_beg + nt + 1;
      const f16* qsrc = qT + (size_t)tn * 64 * 64;
      q0v = *(const uint4*)(qsrc + (size_t)s0r * 64 + s0c);
      q1v = *(const uint4*)(qsrc + (size_t)(s0r + 32) * 64 + s0c);
      v0v = *(const uint4*)(vN + (size_t)s0r * NT + tn * 64 + s0c);
      if (tid < 128)
        v1v = *(const uint4*)(vN + (size_t)(s0r + 32) * NT + tn * 64 + s0c);
    }
    // e for BOTH m-tiles (16 independent MFMA)
    f32x4 ea[4], eb[4];
    __builtin_amdgcn_s_setprio(1);
#pragma unroll
    for (int nf = 0; nf < 4; ++nf) {
      f16x8 a0 = __builtin_bit_cast(f16x8, Qs[(16 * nf + lm) * 8 + c0i]);
      f16x8 a1 = __builtin_bit_cast(f16x8, Qs[(16 * nf + lm) * 8 + c1i]);
      f32x4 ta = {0.f, 0.f, 0.f, 0.f};
      ta = MFMA32(a0, bk0a, ta);
      ta = MFMA32(a1, bk1a, ta);
      ea[nf] = ta;
      f32x4 tb = {0.f, 0.f, 0.f, 0.f};
      tb = MFMA32(a0, bk0b, tb);
      tb = MFMA32(a1, bk1b, tb);
      eb[nf] = tb;
    }
    __builtin_amdgcn_s_setprio(0);
    // exp + pack + write both tiles (A2 loads shared, from LDS)
#pragma unroll
    for (int nf = 0; nf < 4; ++nf) {
      float4 a4 = *(const float4*)&As2[nt * 64 + nf * 16 + g * 4];
      float wa0 = fast_exp2(fmaf(ea[nf][0], -L2E_, a4.x));
      float wa1 = fast_exp2(fmaf(ea[nf][1], -L2E_, a4.y));
      float wa2 = fast_exp2(fmaf(ea[nf][2], -L2E_, a4.z));
      float wa3 = fast_exp2(fmaf(ea[nf][3], -L2E_, a4.w));
      float wb0 = fast_exp2(fmaf(eb[nf][0], -L2E_, a4.x));
      float wb1 = fast_exp2(fmaf(eb[nf][1], -L2E_, a4.y));
      float wb2 = fast_exp2(fmaf(eb[nf][2], -L2E_, a4.z));
      float wb3 = fast_exp2(fmaf(eb[nf][3], -L2E_, a4.w));
      unsigned la = __builtin_bit_cast(unsigned, __builtin_amdgcn_cvt_pkrtz(wa0, wa1));
      unsigned ha = __builtin_bit_cast(unsigned, __builtin_amdgcn_cvt_pkrtz(wa2, wa3));
      unsigned lb = __builtin_bit_cast(unsigned, __builtin_amdgcn_cvt_pkrtz(wb0, wb1));
      unsigned hb = __builtin_bit_cast(unsigned, __builtin_amdgcn_cvt_pkrtz(wb2, wb3));
      int s = 2 * nf + (g >> 1);
      int so = ((s ^ swl) * 2) + (g & 1);
      wt2[wbufa + lm * 16 + so] = make_uint2(la, ha);
      wt2[wbufb + lm * 16 + so] = make_uint2(lb, hb);
    }
    __builtin_amdgcn_sched_barrier(0);  // bounce reads after writes
    f16x8 bw0a = __builtin_bit_cast(f16x8, *(const uint4*)&wt2[rba + c0i * 2]);
    f16x8 bw1a = __builtin_bit_cast(f16x8, *(const uint4*)&wt2[rba + c1i * 2]);
    f16x8 bw0b = __builtin_bit_cast(f16x8, *(const uint4*)&wt2[rbb + c0i * 2]);
    f16x8 bw1b = __builtin_bit_cast(f16x8, *(const uint4*)&wt2[rbb + c1i * 2]);
    __builtin_amdgcn_s_setprio(1);
#pragma unroll
    for (int cf = 0; cf < 3; ++cf) {
      f16x8 av0 = __builtin_bit_cast(f16x8, Vs[(16 * cf + lm) * 8 + c0i]);
      f16x8 av1 = __builtin_bit_cast(f16x8, Vs[(16 * cf + lm) * 8 + c1i]);
      if (cf == 0) {
        oa0 = MFMA32(av0, bw0a, oa0); oa0 = MFMA32(av1, bw1a, oa0);
        ob0 = MFMA32(av0, bw0b, ob0); ob0 = MFMA32(av1, bw1b, ob0);
      }
      if (cf == 1) {
        oa1 = MFMA32(av0, bw0a, oa1); oa1 = MFMA32(av1, bw1a, oa1);
        ob1 = MFMA32(av0, bw0b, ob1); ob1 = MFMA32(av1, bw1b, ob1);
      }
      if (cf == 2) {
        oa2 = MFMA32(av0, bw0a, oa2); oa2 = MFMA32(av1, bw1a, oa2);
        ob2 = MFMA32(av0, bw0b, ob2); ob2 = MFMA32(av1, bw1b, ob2);
      }
    }
    __builtin_amdgcn_s_setprio(0);
    __syncthreads();  // all reads of Qs/Vs done
    if (pf) {
      Qs[sw0] = q0v;
      Qs[sw1] = q1v;
      Vs[sw0] = v0v;
      if (tid < 128) Vs[sw1] = v1v;
    }
    __syncthreads();  // writes visible (also orders wt2 across iters)
  }
  if (NSPLIT == 1) {
#pragma unroll
    for (int r = 0; r < 4; ++r) {
      op[(size_t)(0 + 4 * g + r) * NT + mwa + lm] = oa0[r];
      op[(size_t)(16 + 4 * g + r) * NT + mwa + lm] = oa1[r];
      op[(size_t)(32 + 4 * g + r) * NT + mwa + lm] = oa2[r];
      op[(size_t)(0 + 4 * g + r) * NT + mwb + lm] = ob0[r];
      op[(size_t)(16 + 4 * g + r) * NT + mwb + lm] = ob1[r];
      op[(size_t)(32 + 4 * g + r) * NT + mwb + lm] = ob2[r];
    }
  } else {
#pragma unroll
    for (int r = 0; r < 4; ++r) {
      atomicAdd(&op[(size_t)(0 + 4 * g + r) * NT + mwa + lm], oa0[r]);
      atomicAdd(&op[(size_t)(16 + 4 * g + r) * NT + mwa + lm], oa1[r]);
      atomicAdd(&op[(size_t)(32 + 4 * g + r) * NT + mwa + lm], oa2[r]);
      atomicAdd(&op[(size_t)(0 + 4 * g + r) * NT + mwb + lm], ob0[r]);
      atomicAdd(&op[(size_t)(16 + 4 * g + r) * NT + mwb + lm], ob1[r]);
      atomicAdd(&op[(size_t)(32 + 4 * g + r) * NT + mwb + lm], ob2[r]);
    }
  }
}

// ---------------- merged PV: blocks [0,1024) global, [1024,1600) patch
__global__ __launch_bounds__(256, 4) void k_pv_all(
    const f16* __restrict__ pg_t, const f16* __restrict__ pg_n,
    const float* __restrict__ statsg, float* __restrict__ cat,
    const f16* __restrict__ pp_t, const f16* __restrict__ pp_n,
    const float* __restrict__ statsp, float* __restrict__ pcat) {
  __shared__ float As2[1024];
  __shared__ uint4 Qs[512];
  __shared__ uint4 Vs[384];
  __shared__ uint2 wt2[2048];
  int bid = blockIdx.x;
  if (bid < 1024) {
    pv_body<N_, 4, false>(pg_t, pg_t, pg_n, statsg, cat, bid & 31, bid >> 5,
                          As2, Qs, Vs, wt2);
  } else {
    int pid = bid - 1024;
    pv_body<NP_, 1, true>(pp_t, pp_t, pp_n, statsp, pcat, pid & 7, pid >> 3,
                          As2, Qs, Vs, wt2);
  }
}

// ---------------- LDS-tiled fuse: blocks [0,128) global, [128,416) patch
__global__ __launch_bounds__(256) void k_fuse2(
    const float* __restrict__ cat, const float* __restrict__ fw,
    const float* __restrict__ fb, const float* __restrict__ fg,
    const float* __restrict__ fbb, const float* __restrict__ fm,
    const float* __restrict__ fv, const float* __restrict__ gamma_all,
    const float* __restrict__ input, float* __restrict__ comb,
    const float* __restrict__ pcat, const float* __restrict__ pfw,
    const float* __restrict__ pfb, const float* __restrict__ pfg,
    const float* __restrict__ pfbb, const float* __restrict__ pfm,
    const float* __restrict__ pfv, const float* __restrict__ gamma_p) {
  __shared__ float panel[192 * 64];  // 48 KB
  int tid = threadIdx.x;
  int bid = blockIdx.x;
  int n = tid & 63, og = tid >> 6;  // wave-uniform og (4 groups of 12 outputs)
  if (bid < 128) {
    int b = bid >> 6;          // 64 blocks per batch
    int n0 = (bid & 63) * 64;
    const float* src = cat + (size_t)b * C4_ * N_ + n0;
    for (int i = tid; i < 3072; i += 256) {
      int c = i >> 4, j = (i & 15) * 4;
      *(float4*)&panel[c * 64 + j] = *(const float4*)(src + (size_t)c * N_ + j);
    }
    __syncthreads();
    float acc[12] = {0.f, 0.f, 0.f, 0.f, 0.f, 0.f, 0.f, 0.f, 0.f, 0.f, 0.f, 0.f};
    const float* wbase = fw + (size_t)(og * 12) * C4_;
    for (int c = 0; c < C4_; ++c) {
      float xv = panel[c * 64 + n];
#pragma unroll
      for (int k = 0; k < 12; ++k)
        acc[k] = fmaf(wbase[(size_t)k * C4_ + c], xv, acc[k]);
    }
    float ga = gamma_all[0];
#pragma unroll
    for (int k = 0; k < 12; ++k) {
      int o = og * 12 + k;
      float scale = fg[o] * rsqrtf(fv[o] + EPS_);
      float y = (acc[k] + fb[o] - fm[o]) * scale + fbb[o];
      size_t oi = ((size_t)(b * C_ + o)) * N_ + n0 + n;
      atomicAdd(&comb[oi], input[oi] + ga * fmaxf(y, 0.f));
    }
  } else {
    int pid = bid - 128;       // 288 blocks: 16 per (p,b)-slice
    int slice = pid >> 4;      // = p*2 + b
    int t0 = (pid & 15) * 64;
    int p = slice >> 1, b = slice & 1;
    const float* src = pcat + (size_t)slice * C4_ * NP_ + t0;
    for (int i = tid; i < 3072; i += 256) {
      int c = i >> 4, j = (i & 15) * 4;
      *(float4*)&panel[c * 64 + j] = *(const float4*)(src + (size_t)c * NP_ + j);
    }
    __syncthreads();
    float acc[12] = {0.f, 0.f, 0.f, 0.f, 0.f, 0.f, 0.f, 0.f, 0.f, 0.f, 0.f, 0.f};
    const float* wbase = pfw + ((size_t)p * C_ + og * 12) * C4_;
    for (int c = 0; c < C4_; ++c) {
      float xv = panel[c * 64 + n];
#pragma unroll
      for (int k = 0; k < 12; ++k)
        acc[k] = fmaf(wbase[(size_t)k * C4_ + c], xv, acc[k]);
    }
    int t = t0 + n;
    int r0 = (p / 3) * 16, c0w = (p % 3) * 16;
    int h = r0 + (t >> 5), w = c0w + (t & 31);
    float gp = 0.5f * gamma_p[p];
#pragma unroll
    for (int k = 0; k < 12; ++k) {
      int o = og * 12 + k;
      int po = p * C_ + o;
      float scale = pfg[po] * rsqrtf(pfv[po] + EPS_);
      float y = (acc[k] + pfb[po] - pfm[po]) * scale + pfbb[po];
      atomicAdd(&comb[((size_t)(b * C_ + o)) * N_ + h * 64 + w], gp * fmaxf(y, 0.f));
    }
  }
}

// ---------------- 3x3 conv (SAME) + BN + relu, LDS-tiled (fp32 input)
__global__ __launch_bounds__(256) void k_conv2(
    const float* __restrict__ comb, const float* __restrict__ cw,
    const float* __restrict__ cb, const float* __restrict__ cg,
    const float* __restrict__ cbb, const float* __restrict__ cm,
    const float* __restrict__ cv, float* __restrict__ out) {
  __shared__ float4 inh[4608];  // [c=48][r=6][u=16]
  int tid = threadIdx.x;
  int h0 = blockIdx.x * 4, ocg = blockIdx.y, b = blockIdx.z;
  for (int i = tid; i < 4608; i += 256) {
    int c = i / 96;
    int rem = i - c * 96;
    int r = rem >> 4, u = rem & 15;
    int hh = h0 - 1 + r;
    float4 val = make_float4(0.f, 0.f, 0.f, 0.f);
    if (hh >= 0 && hh < H_)
      val = *(const float4*)(comb + (((size_t)(b * C_ + c) * H_ + hh) * W_ + u * 4));
    inh[i] = val;
  }
  __syncthreads();
  int w = tid & 63, dh = tid >> 6;
  float acc[6] = {0.f, 0.f, 0.f, 0.f, 0.f, 0.f};
  const float* lds = (const float*)inh;
  int wm = w > 0 ? w - 1 : 0;
  int wp = w < 63 ? w + 1 : 63;
  for (int c = 0; c < 48; ++c) {
    float v[9];
#pragma unroll
    for (int r = 0; r < 3; ++r) {
      const float* row = lds + (size_t)(c * 6 + dh + r) * 64;
      float lf = row[wm];
      float md = row[w];
      float rt = row[wp];
      v[r * 3 + 0] = (w > 0) ? lf : 0.f;
      v[r * 3 + 1] = md;
      v[r * 3 + 2] = (w < 63) ? rt : 0.f;
    }
#pragma unroll
    for (int j = 0; j < 6; ++j) {
      const float* wr = cw + (size_t)((ocg * 6 + j) * 48 + c) * 9;
#pragma unroll
      for (int k = 0; k < 9; ++k) acc[j] = fmaf(v[k], wr[k], acc[j]);
    }
  }
#pragma unroll
  for (int j = 0; j < 6; ++j) {
    int o = ocg * 6 + j;
    float scale = cg[o] * rsqrtf(cv[o] + EPS_);
    float y = (acc[j] + cb[o] - cm[o]) * scale + cbb[o];
    out[(size_t)(b * C_ + o) * N_ + (h0 + dh) * 64 + w] = fmaxf(y, 0.f);
  }
}

extern "C" void kernel_launch(void* const* d_in, const int* in_sizes, int n_in,
                              void* d_out, int out_size, void* d_ws, size_t ws_size,
                              hipStream_t stream) {
  (void)in_sizes; (void)n_in; (void)out_size; (void)ws_size;
  const float* x[4];
  const float* Wall[4];
  const float* Wp[4];
  for (int i = 0; i < 4; ++i) {
    x[i] = (const float*)d_in[i];
    Wall[i] = (const float*)d_in[4 + i];
    Wp[i] = (const float*)d_in[8 + i];
  }
  const float* fuse_w = (const float*)d_in[12];
  const float* fuse_b = (const float*)d_in[13];
  const float* fuse_g = (const float*)d_in[14];
  const float* fuse_bb = (const float*)d_in[15];
  const float* fuse_m = (const float*)d_in[16];
  const float* fuse_v = (const float*)d_in[17];
  const float* fuseP_w = (const float*)d_in[18];
  const float* fuseP_b = (const float*)d_in[19];
  const float* fuseP_g = (const float*)d_in[20];
  const float* fuseP_bb = (const float*)d_in[21];
  const float* fuseP_m = (const float*)d_in[22];
  const float* fuseP_v = (const float*)d_in[23];
  const float* gamma_all = (const float*)d_in[24];
  const float* gamma_p = (const float*)d_in[25];
  const float* out_w = (const float*)d_in[26];
  const float* out_b = (const float*)d_in[27];
  const float* out_g = (const float*)d_in[28];
  const float* out_bb = (const float*)d_in[29];
  const float* out_m = (const float*)d_in[30];
  const float* out_v = (const float*)d_in[31];

  char* base = (char*)d_ws;
  size_t off = 0;
  auto carve = [&](size_t bytes) {
    char* p = base + off;
    off += (bytes + 255) & ~(size_t)255;
    return p;
  };
  f16* projg_n = (f16*)carve((size_t)8 * 48 * N_ * 2);
  f16* projg_t = (f16*)carve((size_t)8 * N_ * 64 * 2);
  f16* projp_n = (f16*)carve((size_t)72 * 48 * NP_ * 2);
  f16* projp_t = (f16*)carve((size_t)72 * NP_ * 64 * 2);
  float* stpg = (float*)carve((size_t)8 * N_ * 4 * 4);
  float* stpp = (float*)carve((size_t)72 * NP_ * 4);
  float* statsg = (float*)carve((size_t)8 * N_ * 4);
  float* statsp = (float*)carve((size_t)72 * NP_ * 4);
  float* cat = (float*)carve((size_t)B_ * C4_ * N_ * 4);
  float* pcat = (float*)carve((size_t)9 * B_ * C4_ * NP_ * 4);
  float* comb = (float*)carve((size_t)B_ * C_ * N_ * 4);

  dim3 blk(256);

  (void)hipMemsetAsync(cat, 0, (size_t)B_ * C4_ * N_ * sizeof(float), stream);
  (void)hipMemsetAsync(comb, 0, (size_t)B_ * C_ * N_ * sizeof(float), stream);
  k_proj_all<<<dim3(416), blk, 0, stream>>>(
      x[0], x[1], x[2], x[3], Wall[0], Wall[1], Wall[2], Wall[3],
      Wp[0], Wp[1], Wp[2], Wp[3], projg_n, projg_t, projp_n, projp_t);

  k_stats_all<<<dim3(1600), blk, 0, stream>>>(projg_t, stpg, projp_t, stpp);
  k_merge_all<<<dim3((8 * N_ + 72 * NP_ + 255) / 256), blk, 0, stream>>>(
      stpg, statsg, stpp, statsp);

  k_pv_all<<<dim3(1600), blk, 0, stream>>>(
      projg_t, projg_n, statsg, cat, projp_t, projp_n, statsp, pcat);

  k_fuse2<<<dim3(416), blk, 0, stream>>>(
      cat, fuse_w, fuse_b, fuse_g, fuse_bb, fuse_m, fuse_v, gamma_all, x[0], comb,
      pcat, fuseP_w, fuseP_b, fuseP_g, fuseP_bb, fuseP_m, fuseP_v, gamma_p);
  k_conv2<<<dim3(16, 8, 2), blk, 0, stream>>>(
      comb, out_w, out_b, out_g, out_bb, out_m, out_v, (float*)d_out);
}